// Round 5
// baseline (203.166 us; speedup 1.0000x reference)
//
#include <hip/hip_runtime.h>
#include <hip/hip_bf16.h>
#include <stdint.h>

// Problem constants (fixed by reference setup_inputs)
constexpr int E_NUM  = 8;
constexpr int I_DIM  = 1024;
constexpr int O_DIM  = 1024;
constexpr int B_SEG  = 16;
constexpr int N_ROWS = 16384;

// GEMM tiling: 256x256 tile, BK=64, 512 threads = 8 waves (2 M x 4 N)
constexpr int BM = 256, BN = 256, BK = 64;
constexpr int NT = I_DIM / BK;          // 16 K-tiles

typedef __bf16 bf16x8 __attribute__((ext_vector_type(8)));
typedef float  f32x4  __attribute__((ext_vector_type(4)));
typedef unsigned short ushortx4 __attribute__((ext_vector_type(4)));
typedef unsigned int   u32x4    __attribute__((ext_vector_type(4)));

#define AS1 __attribute__((address_space(1)))
#define AS3 __attribute__((address_space(3)))

__device__ __forceinline__ unsigned short f2bf(float f) {
    unsigned int u = __float_as_uint(f);
    u += 0x7fffu + ((u >> 16) & 1u);
    return (unsigned short)(u >> 16);
}

// ---------------------------------------------------------------------------
// prep: synth_w ONLY (cvt_x is fused into the GEMM's A-staging now).
// 512 blocks x 256 threads x 2 float4 slots; w read exactly once (32 MB),
// wb written once (32 MB). Lane-contiguous 16 B loads / 8 B stores.
// ---------------------------------------------------------------------------
__global__ __launch_bounds__(256) void prep(const float* __restrict__ w,
                                            const float* __restrict__ coeff,
                                            unsigned short* __restrict__ wb) {
    __shared__ float sc[B_SEG * E_NUM];
    const int tid = threadIdx.x;
    if (tid < B_SEG * E_NUM) sc[tid] = coeff[tid];
    __syncthreads();

    const size_t s0 = (size_t)blockIdx.x * 512 + tid;    // float4 slot
    const size_t s1 = s0 + 256;
    float4 wv0[E_NUM], wv1[E_NUM];
#pragma unroll
    for (int e = 0; e < E_NUM; e++) {
        wv0[e] = *(const float4*)(w + (size_t)e * O_DIM * I_DIM + s0 * 4);
        wv1[e] = *(const float4*)(w + (size_t)e * O_DIM * I_DIM + s1 * 4);
    }

#pragma unroll
    for (int b = 0; b < B_SEG; b++) {
        float a0 = 0.f, a1 = 0.f, a2 = 0.f, a3 = 0.f;
        float c0 = 0.f, c1 = 0.f, c2 = 0.f, c3 = 0.f;
#pragma unroll
        for (int e = 0; e < E_NUM; e++) {
            const float c = sc[b * E_NUM + e];
            a0 += c * wv0[e].x; a1 += c * wv0[e].y;
            a2 += c * wv0[e].z; a3 += c * wv0[e].w;
            c0 += c * wv1[e].x; c1 += c * wv1[e].y;
            c2 += c * wv1[e].z; c3 += c * wv1[e].w;
        }
        ushortx4 o0, o1;
        o0[0] = f2bf(a0); o0[1] = f2bf(a1); o0[2] = f2bf(a2); o0[3] = f2bf(a3);
        o1[0] = f2bf(c0); o1[1] = f2bf(c1); o1[2] = f2bf(c2); o1[3] = f2bf(c3);
        *(ushortx4*)(wb + (size_t)b * O_DIM * I_DIM + s0 * 4) = o0;
        *(ushortx4*)(wb + (size_t)b * O_DIM * I_DIM + s1 * 4) = o1;
    }
}

// ---------------------------------------------------------------------------
// opaque LDS read (rule 18: manual lgkmcnt + sched_barrier afterwards)
// ---------------------------------------------------------------------------
__device__ __forceinline__ bf16x8 lds_read_b128(unsigned addr) {
    bf16x8 r;
    asm volatile("ds_read_b128 %0, %1" : "=v"(r) : "v"(addr));
    return r;
}
__device__ __forceinline__ void lds_write_b128(unsigned addr, u32x4 v) {
    asm volatile("ds_write_b128 %0, %1" :: "v"(addr), "v"(v) : "memory");
}
__device__ __forceinline__ unsigned cvt_pk_bf16(float lo, float hi) {
    unsigned r;
    asm("v_cvt_pk_bf16_f32 %0, %1, %2" : "=v"(r) : "v"(lo), "v"(hi));
    return r;
}

// ---------------------------------------------------------------------------
// Kernel 2: per-segment GEMM, C = X * W_seg^T + bias, with A-conversion
// (fp32 x -> bf16) FUSED into staging. 256x256 tile, BK=64, 8 waves.
// B-halves: global_load_lds from bf16 wb (source-swizzled, as before).
// A-halves: reg-staged (T14): 4x global_load_dwordx4 fp32 issued 2 phases
// ahead -> v_cvt_pk_bf16_f32 -> 2x ds_write_b128 at the swizzled LDS
// position (q^(r&7)) -- byte-identical layout to the old gload_lds path,
// so the ds_read side is unchanged.
// vmcnt ledger (issue order per tile: a0(4 reg) b0(2 lds) a1(4 reg) b1(2 lds)):
//   ph0-end  vmcnt(4): retires prev-tile b1   (asm; compiler can't see lds deps)
//   ph2      compiler-inserted wait before cvt(rA0) retires a0
//   ph3      vmcnt(2): retires b0 (+a1)       (asm)
// ds_writes lgkm-drained before each publishing barrier.
// ---------------------------------------------------------------------------
__global__ __launch_bounds__(512, 2) void gemm_moe(
    const float* __restrict__ x,             // [N][I] fp32
    const unsigned short* __restrict__ wb,   // [B][O][I] bf16 bits
    const float* __restrict__ bias,          // [O]
    const int* __restrict__ msz,             // [B]
    float* __restrict__ out)                 // [N][O] fp32
{
    __shared__ __align__(16) char sLDS[131072];   // A: 4x16KB, B: 4x16KB

    // ---- XCD-aware mapping: 256 blocks, lid%8 = XCD, 2 segments per XCD,
    // 4x4 tiles of 256^2 per segment (all 16 blocks of a segment on 1 XCD).
    const int lid  = blockIdx.x;            // 0..255
    const int xcd  = lid & 7;
    const int idx  = lid >> 3;              // 0..31
    const int seg  = (xcd << 1) | (idx >> 4);
    const int t16  = idx & 15;
    const int mblk = t16 >> 2;
    const int nblk = t16 & 3;

    int off = 0;
    for (int b = 0; b < seg; b++) off += msz[b];
    const int row0 = off + mblk * BM;
    const int col0 = nblk * BN;
    const unsigned short* wseg = wb + (size_t)seg * O_DIM * I_DIM;

    const int tid  = threadIdx.x;
    const int wave = tid >> 6;              // 0..7
    const int lane = tid & 63;
    const int wr = wave >> 2, wc = wave & 3;
    const int quad = lane >> 4, l16 = lane & 15;

    // ---- B staging (unchanged): source-swizzled global_load_lds.
    const int srow8  = lane >> 3;                       // 0..7
    const int schunk = (lane & 7) ^ srow8;              // swizzled K-chunk
    const unsigned short* gB0 = wseg + (size_t)(col0 + wave * 8 + srow8) * I_DIM + schunk * 8;
    const unsigned short* gB1 = gB0 + (size_t)128 * I_DIM;

    // ---- A staging (new): 512 threads cover one 128x64-fp32 half-tile.
    // Thread t: row arow = t>>2 (0..127), col-pair acpair = t&3 -> owns
    // chunks q0=2*acpair, q1=2*acpair+1 (16 floats). LDS write position of
    // chunk q in row r is (q ^ (r&7)) -- identical bytes to the old layout.
    const int arow   = tid >> 2;
    const int acpair = tid & 3;
    const float* xA = x + (size_t)(row0 + arow) * I_DIM + acpair * 16;
    const unsigned awr = (unsigned)(arow * 128);
    const unsigned aw0 = (unsigned)(((2 * acpair)     ^ (arow & 7)) * 16);
    const unsigned aw1 = (unsigned)(((2 * acpair + 1) ^ (arow & 7)) * 16);

    // ---- ds_read lane addresses (bytes) -- unchanged.
    const unsigned rdA0 = (unsigned)((wr * 16 + l16) * 128 + (((0 + quad) ^ (l16 & 7)) * 16));
    const unsigned rdA1 = (unsigned)((wr * 16 + l16) * 128 + (((4 + quad) ^ (l16 & 7)) * 16));
    const unsigned rdB0 = (unsigned)(65536 + (wc * 16 + l16) * 128 + (((0 + quad) ^ (l16 & 7)) * 16));
    const unsigned rdB1 = (unsigned)(65536 + (wc * 16 + l16) * 128 + (((4 + quad) ^ (l16 & 7)) * 16));

    bf16x8 af0[4][2], af1[4][2], b0[2][2], b1[2][2];
    float4 rA0_0, rA0_1, rA0_2, rA0_3;      // named regs (rule 20)
    float4 rA1_0, rA1_1, rA1_2, rA1_3;
    f32x4 acc[8][4];
#pragma unroll
    for (int m = 0; m < 8; ++m)
#pragma unroll
        for (int n = 0; n < 4; ++n)
            acc[m][n] = (f32x4){0.f, 0.f, 0.f, 0.f};

#define LOAD_A(DST, S) do { _Pragma("unroll") for (int mm = 0; mm < 4; ++mm) {      \
        DST[mm][0] = lds_read_b128(rdA0 + (S) * 16384u + mm * 4096u);               \
        DST[mm][1] = lds_read_b128(rdA1 + (S) * 16384u + mm * 4096u); } } while (0)
#define LOAD_B(DST, S) do { _Pragma("unroll") for (int nn = 0; nn < 2; ++nn) {      \
        DST[nn][0] = lds_read_b128(rdB0 + (S) * 16384u + nn * 8192u);               \
        DST[nn][1] = lds_read_b128(rdB1 + (S) * 16384u + nn * 8192u); } } while (0)

// issue 4 fp32 A-loads (64 B/thread) for half H of K-tile ST into named regs
#define A_ISSUE(P, H, ST) do {                                                      \
        const float* g_ = xA + (size_t)(H) * 128 * I_DIM + (ST) * 64;               \
        P##_0 = *(const float4*)(g_);                                               \
        P##_1 = *(const float4*)(g_ + 4);                                           \
        P##_2 = *(const float4*)(g_ + 8);                                           \
        P##_3 = *(const float4*)(g_ + 12); } while (0)

// convert 16 floats -> bf16, write 2 chunks at swizzled positions in slot S
#define A_WRITE(P, S) do {                                                          \
        u32x4 u0_, u1_;                                                             \
        u0_[0] = cvt_pk_bf16(P##_0.x, P##_0.y); u0_[1] = cvt_pk_bf16(P##_0.z, P##_0.w); \
        u0_[2] = cvt_pk_bf16(P##_1.x, P##_1.y); u0_[3] = cvt_pk_bf16(P##_1.z, P##_1.w); \
        u1_[0] = cvt_pk_bf16(P##_2.x, P##_2.y); u1_[1] = cvt_pk_bf16(P##_2.z, P##_2.w); \
        u1_[2] = cvt_pk_bf16(P##_3.x, P##_3.y); u1_[3] = cvt_pk_bf16(P##_3.z, P##_3.w); \
        lds_write_b128((S) * 16384u + awr + aw0, u0_);                              \
        lds_write_b128((S) * 16384u + awr + aw1, u1_); } while (0)

#define STAGE_B(H, S, ST) do {                                                      \
        const unsigned short* g_ = ((H) ? gB1 : gB0) + (size_t)(ST) * 64;           \
        __builtin_amdgcn_global_load_lds((const AS1 void*)g_,                       \
            (AS3 void*)(sLDS + 65536 + (S) * 16384 + wave * 1024), 16, 0, 0);       \
        __builtin_amdgcn_global_load_lds((const AS1 void*)(g_ + (size_t)64 * I_DIM),\
            (AS3 void*)(sLDS + 65536 + (S) * 16384 + 8192 + wave * 1024), 16, 0, 0); } while (0)

#define MFMA_Q(MH, NH, A, BV) do { _Pragma("unroll") for (int mm = 0; mm < 4; ++mm) \
        _Pragma("unroll") for (int nn = 0; nn < 2; ++nn)                            \
        _Pragma("unroll") for (int kk = 0; kk < 2; ++kk)                            \
            acc[(MH) * 4 + mm][(NH) * 2 + nn] =                                     \
                __builtin_amdgcn_mfma_f32_16x16x32_bf16(A[mm][kk], BV[nn][kk],      \
                    acc[(MH) * 4 + mm][(NH) * 2 + nn], 0, 0, 0); } while (0)

#define PH_MID() do { __builtin_amdgcn_sched_barrier(0);                            \
        __builtin_amdgcn_s_barrier();                                               \
        asm volatile("s_waitcnt lgkmcnt(0)");                                       \
        __builtin_amdgcn_sched_barrier(0);                                          \
        __builtin_amdgcn_s_setprio(1); } while (0)

    // TILE: read slots R0 (h0) / R1 (h1); stage tile ST into S0, S1.
#define TILE(R0, R1, S0, S1, ST) do {                                               \
        /* ph0: A-h0 loads issued; compute (mh0,nh0) */                             \
        A_ISSUE(rA0, 0, ST);                                                        \
        LOAD_A(af0, R0); LOAD_B(b0, R0);                                            \
        PH_MID(); MFMA_Q(0, 0, af0, b0);                                            \
        __builtin_amdgcn_s_setprio(0); __builtin_amdgcn_sched_barrier(0);           \
        asm volatile("s_waitcnt vmcnt(4)");   /* retire prev-tile b1 */             \
        __builtin_amdgcn_sched_barrier(0); __builtin_amdgcn_s_barrier();            \
        /* ph1: B-h0 staged; compute (mh1,nh0) */                                   \
        LOAD_A(af1, R1); STAGE_B(0, S0, ST);                                        \
        PH_MID(); MFMA_Q(1, 0, af1, b0);                                            \
        __builtin_amdgcn_s_setprio(0); __builtin_amdgcn_sched_barrier(0);           \
        __builtin_amdgcn_s_barrier();                                               \
        /* ph2: A-h1 loads issued; compute (mh1,nh1); write A-h0 to LDS */          \
        LOAD_B(b1, R1); A_ISSUE(rA1, 1, ST);                                        \
        PH_MID(); MFMA_Q(1, 1, af1, b1);                                            \
        __builtin_amdgcn_s_setprio(0); __builtin_amdgcn_sched_barrier(0);           \
        A_WRITE(rA0, S0);                     /* compiler waits rA0 loads */        \
        __builtin_amdgcn_sched_barrier(0); __builtin_amdgcn_s_barrier();            \
        /* ph3: B-h1 staged; compute (mh0,nh1); write A-h1 to LDS */                \
        STAGE_B(1, S1, ST);                                                         \
        PH_MID(); MFMA_Q(0, 1, af0, b1);                                            \
        __builtin_amdgcn_s_setprio(0); __builtin_amdgcn_sched_barrier(0);           \
        asm volatile("s_waitcnt vmcnt(2)");   /* retire b0 (+a1) */                 \
        __builtin_amdgcn_sched_barrier(0);                                          \
        A_WRITE(rA1, S1);                                                           \
        asm volatile("s_waitcnt lgkmcnt(0)"); /* drain A-h1 ds_writes */            \
        __builtin_amdgcn_sched_barrier(0); __builtin_amdgcn_s_barrier();            \
    } while (0)

    // ---- prologue: tile0 fully staged (A via regs+cvt, B via gload_lds),
    // full drain, barrier. Loop invariant starts with an empty vmem queue.
    A_ISSUE(rA0, 0, 0);
    A_ISSUE(rA1, 1, 0);
    STAGE_B(0, 0, 0);    // B h0 -> slot 0
    STAGE_B(1, 1, 0);    // B h1 -> slot 1
    A_WRITE(rA0, 0);     // compiler inserts the waits for the fp32 loads
    A_WRITE(rA1, 1);
    asm volatile("s_waitcnt vmcnt(0) lgkmcnt(0)");
    __builtin_amdgcn_sched_barrier(0);
    __builtin_amdgcn_s_barrier();

#pragma unroll 1
    for (int tp = 0; tp < 8; ++tp) {
        const int t0 = 2 * tp, t1 = t0 + 1;
        const int st0 = (t0 + 1 < NT) ? t0 + 1 : NT - 1;   // clamped tail
        const int st1 = (t1 + 1 < NT) ? t1 + 1 : NT - 1;   // keeps credits uniform
        TILE(0, 1, 2, 3, st0);   // even tile: read slots {0,1}, stage {2,3}
        TILE(2, 3, 0, 1, st1);   // odd tile:  read slots {2,3}, stage {0,1}
    }
    asm volatile("s_waitcnt vmcnt(0) lgkmcnt(0)");   // drain tail stages

#undef TILE
#undef PH_MID
#undef MFMA_Q
#undef STAGE_B
#undef A_WRITE
#undef A_ISSUE
#undef LOAD_B
#undef LOAD_A

    // ---- epilogue: C/D layout col=lane&15, row=quad*4+reg; stripe mapping:
    // row = row0 + m*32 + wr*16 + ..., col = col0 + n*64 + wc*16 + l16.
    float bv[4];
#pragma unroll
    for (int n = 0; n < 4; ++n)
        bv[n] = bias[col0 + n * 64 + wc * 16 + l16];

#pragma unroll
    for (int m = 0; m < 8; ++m) {
#pragma unroll
        for (int r = 0; r < 4; ++r) {
            int row = row0 + m * 32 + wr * 16 + quad * 4 + r;
            float* po = out + (size_t)row * O_DIM + col0 + wc * 16 + l16;
#pragma unroll
            for (int n = 0; n < 4; ++n)
                po[n * 64] = acc[m][n][r] + bv[n];
        }
    }
}

// ---------------------------------------------------------------------------
extern "C" void kernel_launch(void* const* d_in, const int* in_sizes, int n_in,
                              void* d_out, int out_size, void* d_ws, size_t ws_size,
                              hipStream_t stream) {
    const float* x     = (const float*)d_in[0];
    const float* w     = (const float*)d_in[1];
    const float* bias  = (const float*)d_in[2];
    const float* coeff = (const float*)d_in[3];
    const int*   msz   = (const int*)d_in[4];
    float* out = (float*)d_out;

    unsigned short* wb = (unsigned short*)d_ws;                    // 32 MB

    prep<<<512, 256, 0, stream>>>(w, coeff, wb);

    gemm_moe<<<B_SEG * (1024 / BM) * (1024 / BN), 512, 0, stream>>>(x, wb, bias, msz, out);
}

// Round 8
// 194.467 us; speedup vs baseline: 1.0447x; 1.0447x over previous
//
#include <hip/hip_runtime.h>
#include <hip/hip_bf16.h>
#include <stdint.h>

// Problem constants (fixed by reference setup_inputs)
constexpr int E_NUM  = 8;
constexpr int I_DIM  = 1024;
constexpr int O_DIM  = 1024;
constexpr int B_SEG  = 16;
constexpr int N_ROWS = 16384;

// GEMM tiling: 256x256 tile, BK=64, 512 threads = 8 waves (2 M x 4 N)
constexpr int BM = 256, BN = 256, BK = 64;
constexpr int NT = I_DIM / BK;          // 16 K-tiles

typedef __bf16 bf16x8 __attribute__((ext_vector_type(8)));
typedef float  f32x4  __attribute__((ext_vector_type(4)));
typedef unsigned short ushortx4 __attribute__((ext_vector_type(4)));

#define AS1 __attribute__((address_space(1)))
#define AS3 __attribute__((address_space(3)))

__device__ __forceinline__ unsigned short f2bf(float f) {
    unsigned int u = __float_as_uint(f);
    u += 0x7fffu + ((u >> 16) & 1u);
    return (unsigned short)(u >> 16);
}

// ---------------------------------------------------------------------------
// Kernel 1: cvt_x — x fp32 -> bf16. Grid-stride, lane-contiguous:
// 16 B/lane float4 reads, 8 B/lane ushortx4 writes. 2048 blocks (G11).
// ---------------------------------------------------------------------------
__global__ __launch_bounds__(256) void cvt_x(const float* __restrict__ x,
                                             unsigned short* __restrict__ xb) {
    const size_t nt4   = (size_t)N_ROWS * I_DIM / 4;       // float4 tasks
    const size_t gsz   = (size_t)gridDim.x * 256;
    size_t i = (size_t)blockIdx.x * 256 + threadIdx.x;
#pragma unroll 2
    for (; i < nt4; i += gsz) {
        const float4 v = *(const float4*)(x + i * 4);
        ushortx4 o;
        o[0] = f2bf(v.x); o[1] = f2bf(v.y); o[2] = f2bf(v.z); o[3] = f2bf(v.w);
        *(ushortx4*)(xb + i * 4) = o;
    }
}

// ---------------------------------------------------------------------------
// Kernel 2: synth_w — W_b[o,i] = sum_e coeff[b,e] * weights[e,o,i], bf16.
// (r5-proven) 512 blocks x 256 threads x 2 float4 slots; w read exactly
// once (32 MB), wb written once (32 MB). Lane-contiguous 16 B / 8 B.
// ---------------------------------------------------------------------------
__global__ __launch_bounds__(256) void synth_w(const float* __restrict__ w,
                                               const float* __restrict__ coeff,
                                               unsigned short* __restrict__ wb) {
    __shared__ float sc[B_SEG * E_NUM];
    const int tid = threadIdx.x;
    if (tid < B_SEG * E_NUM) sc[tid] = coeff[tid];
    __syncthreads();

    const size_t s0 = (size_t)blockIdx.x * 512 + tid;    // float4 slot
    const size_t s1 = s0 + 256;
    float4 wv0[E_NUM], wv1[E_NUM];
#pragma unroll
    for (int e = 0; e < E_NUM; e++) {
        wv0[e] = *(const float4*)(w + (size_t)e * O_DIM * I_DIM + s0 * 4);
        wv1[e] = *(const float4*)(w + (size_t)e * O_DIM * I_DIM + s1 * 4);
    }

#pragma unroll
    for (int b = 0; b < B_SEG; b++) {
        float a0 = 0.f, a1 = 0.f, a2 = 0.f, a3 = 0.f;
        float c0 = 0.f, c1 = 0.f, c2 = 0.f, c3 = 0.f;
#pragma unroll
        for (int e = 0; e < E_NUM; e++) {
            const float c = sc[b * E_NUM + e];
            a0 += c * wv0[e].x; a1 += c * wv0[e].y;
            a2 += c * wv0[e].z; a3 += c * wv0[e].w;
            c0 += c * wv1[e].x; c1 += c * wv1[e].y;
            c2 += c * wv1[e].z; c3 += c * wv1[e].w;
        }
        ushortx4 o0, o1;
        o0[0] = f2bf(a0); o0[1] = f2bf(a1); o0[2] = f2bf(a2); o0[3] = f2bf(a3);
        o1[0] = f2bf(c0); o1[1] = f2bf(c1); o1[2] = f2bf(c2); o1[3] = f2bf(c3);
        *(ushortx4*)(wb + (size_t)b * O_DIM * I_DIM + s0 * 4) = o0;
        *(ushortx4*)(wb + (size_t)b * O_DIM * I_DIM + s1 * 4) = o1;
    }
}

// ---------------------------------------------------------------------------
// opaque LDS read (rule 18: manual lgkmcnt + sched_barrier afterwards)
// ---------------------------------------------------------------------------
__device__ __forceinline__ bf16x8 lds_read_b128(unsigned addr) {
    bf16x8 r;
    asm volatile("ds_read_b128 %0, %1" : "=v"(r) : "v"(addr));
    return r;
}

// ---------------------------------------------------------------------------
// Kernel 3: per-segment GEMM, C = X * W_seg^T + bias. (r4-proven, verbatim)
// 256x256 tile, BK=64, 8 waves (2Mx4N, stripe-interleaved). Full-tile
// double buffer staged at HALF-TILE granularity, one half per phase, into
// the opposite buffer. Staggered consumption: ph0 (mh0,nh0) ph1 (mh1,nh0)
// ph2 (mh1,nh1) ph3 (mh0,nh1 -- A-h0 reused from regs). Counted vmcnt(4)
// at ends of ph0/ph1/ph3. 24 ds_read_b128 per wave per K-tile.
// ---------------------------------------------------------------------------
__global__ __launch_bounds__(512, 2) void gemm_moe(
    const unsigned short* __restrict__ xb,   // [N][I] bf16 bits
    const unsigned short* __restrict__ wb,   // [B][O][I] bf16 bits
    const float* __restrict__ bias,          // [O]
    const int* __restrict__ msz,             // [B]
    float* __restrict__ out)                 // [N][O] fp32
{
    __shared__ __align__(16) char sLDS[131072];   // A: 4x16KB, B: 4x16KB

    // ---- XCD-aware mapping: 256 blocks, lid%8 = XCD, 2 segments per XCD,
    // 4x4 tiles of 256^2 per segment.
    const int lid  = blockIdx.x;            // 0..255
    const int xcd  = lid & 7;
    const int idx  = lid >> 3;              // 0..31
    const int seg  = (xcd << 1) | (idx >> 4);
    const int t16  = idx & 15;
    const int mblk = t16 >> 2;
    const int nblk = t16 & 3;

    int off = 0;
    for (int b = 0; b < seg; b++) off += msz[b];
    const int row0 = off + mblk * BM;
    const int col0 = nblk * BN;
    const unsigned short* wseg = wb + (size_t)seg * O_DIM * I_DIM;

    const int tid  = threadIdx.x;
    const int wave = tid >> 6;              // 0..7
    const int lane = tid & 63;
    const int wr = wave >> 2, wc = wave & 3;
    const int quad = lane >> 4, l16 = lane & 15;

    // ---- staging source geometry: 512 threads cover one 128x64 half-tile
    // with 2 global_load_lds (64 rows each). LDS dest linear; K-chunk XOR
    // swizzle (chunk ^= row&7) applied to the per-lane GLOBAL source.
    const int srow8  = lane >> 3;                       // 0..7
    const int schunk = (lane & 7) ^ srow8;              // swizzled K-chunk
    const unsigned short* gA0 = xb   + (size_t)(row0 + wave * 8 + srow8) * I_DIM + schunk * 8;
    const unsigned short* gA1 = gA0 + (size_t)128 * I_DIM;
    const unsigned short* gB0 = wseg + (size_t)(col0 + wave * 8 + srow8) * I_DIM + schunk * 8;
    const unsigned short* gB1 = gB0 + (size_t)128 * I_DIM;

    // ---- ds_read lane addresses (bytes). Row within half: A: mm*32 +
    // wr*16 + l16 ; B: nn*64 + wc*16 + l16. chunk = (kk*4+quad)^(l16&7).
    const unsigned rdA0 = (unsigned)((wr * 16 + l16) * 128 + (((0 + quad) ^ (l16 & 7)) * 16));
    const unsigned rdA1 = (unsigned)((wr * 16 + l16) * 128 + (((4 + quad) ^ (l16 & 7)) * 16));
    const unsigned rdB0 = (unsigned)(65536 + (wc * 16 + l16) * 128 + (((0 + quad) ^ (l16 & 7)) * 16));
    const unsigned rdB1 = (unsigned)(65536 + (wc * 16 + l16) * 128 + (((4 + quad) ^ (l16 & 7)) * 16));

    bf16x8 af0[4][2], af1[4][2], b0[2][2], b1[2][2];
    f32x4 acc[8][4];
#pragma unroll
    for (int m = 0; m < 8; ++m)
#pragma unroll
        for (int n = 0; n < 4; ++n)
            acc[m][n] = (f32x4){0.f, 0.f, 0.f, 0.f};

#define LOAD_A(DST, S) do { _Pragma("unroll") for (int mm = 0; mm < 4; ++mm) {      \
        DST[mm][0] = lds_read_b128(rdA0 + (S) * 16384u + mm * 4096u);               \
        DST[mm][1] = lds_read_b128(rdA1 + (S) * 16384u + mm * 4096u); } } while (0)
#define LOAD_B(DST, S) do { _Pragma("unroll") for (int nn = 0; nn < 2; ++nn) {      \
        DST[nn][0] = lds_read_b128(rdB0 + (S) * 16384u + nn * 8192u);               \
        DST[nn][1] = lds_read_b128(rdB1 + (S) * 16384u + nn * 8192u); } } while (0)

#define STAGE_A(H, S, ST) do {                                                      \
        const unsigned short* g_ = ((H) ? gA1 : gA0) + (size_t)(ST) * 64;           \
        __builtin_amdgcn_global_load_lds((const AS1 void*)g_,                       \
            (AS3 void*)(sLDS + (S) * 16384 + wave * 1024), 16, 0, 0);               \
        __builtin_amdgcn_global_load_lds((const AS1 void*)(g_ + (size_t)64 * I_DIM),\
            (AS3 void*)(sLDS + (S) * 16384 + 8192 + wave * 1024), 16, 0, 0); } while (0)
#define STAGE_B(H, S, ST) do {                                                      \
        const unsigned short* g_ = ((H) ? gB1 : gB0) + (size_t)(ST) * 64;           \
        __builtin_amdgcn_global_load_lds((const AS1 void*)g_,                       \
            (AS3 void*)(sLDS + 65536 + (S) * 16384 + wave * 1024), 16, 0, 0);       \
        __builtin_amdgcn_global_load_lds((const AS1 void*)(g_ + (size_t)64 * I_DIM),\
            (AS3 void*)(sLDS + 65536 + (S) * 16384 + 8192 + wave * 1024), 16, 0, 0); } while (0)

#define MFMA_Q(MH, NH, A, BV) do { _Pragma("unroll") for (int mm = 0; mm < 4; ++mm) \
        _Pragma("unroll") for (int nn = 0; nn < 2; ++nn)                            \
        _Pragma("unroll") for (int kk = 0; kk < 2; ++kk)                            \
            acc[(MH) * 4 + mm][(NH) * 2 + nn] =                                     \
                __builtin_amdgcn_mfma_f32_16x16x32_bf16(A[mm][kk], BV[nn][kk],      \
                    acc[(MH) * 4 + mm][(NH) * 2 + nn], 0, 0, 0); } while (0)

#define PH_MID() do { __builtin_amdgcn_sched_barrier(0);                            \
        __builtin_amdgcn_s_barrier();                                               \
        asm volatile("s_waitcnt lgkmcnt(0)");                                       \
        __builtin_amdgcn_sched_barrier(0);                                          \
        __builtin_amdgcn_s_setprio(1); } while (0)
#define PH_END_W() do { __builtin_amdgcn_s_setprio(0);                              \
        __builtin_amdgcn_sched_barrier(0);                                          \
        asm volatile("s_waitcnt vmcnt(4)");                                         \
        __builtin_amdgcn_sched_barrier(0);                                          \
        __builtin_amdgcn_s_barrier(); } while (0)
#define PH_END_N() do { __builtin_amdgcn_s_setprio(0);                              \
        __builtin_amdgcn_sched_barrier(0);                                          \
        __builtin_amdgcn_s_barrier(); } while (0)

    // TILE: read A/B halves from slots R0 (h0), R1 (h1); stage tile t+1's
    // four halves (one per phase) into slots S0, S1.
#define TILE(R0, R1, S0, S1, ST) do {                                               \
        LOAD_A(af0, R0); LOAD_B(b0, R0); STAGE_A(0, S0, ST);                        \
        PH_MID(); MFMA_Q(0, 0, af0, b0); PH_END_W();                                \
        LOAD_A(af1, R1); STAGE_B(0, S0, ST);                                        \
        PH_MID(); MFMA_Q(1, 0, af1, b0); PH_END_W();                                \
        LOAD_B(b1, R1); STAGE_A(1, S1, ST);                                         \
        PH_MID(); MFMA_Q(1, 1, af1, b1); PH_END_N();                                \
        STAGE_B(1, S1, ST);                                                         \
        PH_MID(); MFMA_Q(0, 1, af0, b1); PH_END_W();                                \
    } while (0)

    // ---- prologue: tile0's four halves into slots 0,0,1,1; vmcnt(4)
    // retires Ah0,Bh0 -- Ah1,Bh1 still in flight.
    STAGE_A(0, 0, 0); STAGE_B(0, 0, 0);
    STAGE_A(1, 1, 0); STAGE_B(1, 1, 0);
    asm volatile("s_waitcnt vmcnt(4)");
    __builtin_amdgcn_sched_barrier(0);
    __builtin_amdgcn_s_barrier();

#pragma unroll 1
    for (int tp = 0; tp < 8; ++tp) {
        const int t0 = 2 * tp, t1 = t0 + 1;
        const int st0 = (t0 + 1 < NT) ? t0 + 1 : NT - 1;   // clamped tail
        const int st1 = (t1 + 1 < NT) ? t1 + 1 : NT - 1;   // keeps credits uniform
        TILE(0, 1, 2, 3, st0);   // even tile: read slots {0,1}, stage {2,3}
        TILE(2, 3, 0, 1, st1);   // odd tile:  read slots {2,3}, stage {0,1}
    }

#undef TILE
#undef PH_END_N
#undef PH_END_W
#undef PH_MID
#undef MFMA_Q
#undef STAGE_B
#undef STAGE_A
#undef LOAD_B
#undef LOAD_A

    // ---- epilogue: C/D layout col=lane&15, row=quad*4+reg; stripe mapping:
    // row = row0 + m*32 + wr*16 + ..., col = col0 + n*64 + wc*16 + l16.
    float bv[4];
#pragma unroll
    for (int n = 0; n < 4; ++n)
        bv[n] = bias[col0 + n * 64 + wc * 16 + l16];

#pragma unroll
    for (int m = 0; m < 8; ++m) {
#pragma unroll
        for (int r = 0; r < 4; ++r) {
            int row = row0 + m * 32 + wr * 16 + quad * 4 + r;
            float* po = out + (size_t)row * O_DIM + col0 + wc * 16 + l16;
#pragma unroll
            for (int n = 0; n < 4; ++n)
                po[n * 64] = acc[m][n][r] + bv[n];
        }
    }
}

// ---------------------------------------------------------------------------
extern "C" void kernel_launch(void* const* d_in, const int* in_sizes, int n_in,
                              void* d_out, int out_size, void* d_ws, size_t ws_size,
                              hipStream_t stream) {
    const float* x     = (const float*)d_in[0];
    const float* w     = (const float*)d_in[1];
    const float* bias  = (const float*)d_in[2];
    const float* coeff = (const float*)d_in[3];
    const int*   msz   = (const int*)d_in[4];
    float* out = (float*)d_out;

    unsigned short* xb = (unsigned short*)d_ws;                    // 32 MB
    unsigned short* wb = xb + (size_t)N_ROWS * I_DIM;              // 32 MB

    cvt_x<<<2048, 256, 0, stream>>>(x, xb);
    synth_w<<<512, 256, 0, stream>>>(w, coeff, wb);

    gemm_moe<<<B_SEG * (1024 / BM) * (1024 / BN), 512, 0, stream>>>(xb, wb, bias, msz, out);
}